// Round 1
// baseline (191.538 us; speedup 1.0000x reference)
//
#include <hip/hip_runtime.h>
#include <hip/hip_bf16.h>
#include <hip/hip_fp16.h>

typedef _Float16 half8 __attribute__((ext_vector_type(8)));
typedef float floatx4 __attribute__((ext_vector_type(4)));
typedef unsigned short u16;
typedef unsigned int u32;

#define LEAKY 0.2f
#define MASKV -9.0e15f

// ---------------- Kernel A: h_ds[b][d] = (mean of 150 rows) @ wd ----------------
__global__ __launch_bounds__(128) void k_hds(const float* __restrict__ hl,
                                             const float* __restrict__ ht,
                                             const float* __restrict__ ie,
                                             const float* __restrict__ wd,
                                             float* __restrict__ hds) {
  int b = blockIdx.x, d = threadIdx.x;
  const size_t base = (size_t)b * 50 * 128 + d;
  float acc = 0.f;
  for (int l2 = 0; l2 < 50; ++l2) {
    size_t o = base + (size_t)l2 * 128;
    acc += hl[o] + ht[o] + ie[o];
  }
  __shared__ float ml[128];
  ml[d] = acc * (1.0f / 150.0f);
  __syncthreads();
  float o = 0.f;
  for (int k = 0; k < 128; ++k) o = fmaf(ml[k], wd[k * 128 + d], o);
  hds[b * 128 + d] = o;
}

// ---------------- Kernel B: s[b][i][4], h16[b][i][d], h16T[b][d][i] ----------------
__global__ __launch_bounds__(256) void k_prep(const float* __restrict__ h,
                                              const float* __restrict__ hds,
                                              const float* __restrict__ a0,
                                              const float* __restrict__ a1,
                                              const float* __restrict__ a2,
                                              const float* __restrict__ a3,
                                              float* __restrict__ s,
                                              u16* __restrict__ h16,
                                              u16* __restrict__ h16T) {
  int b = blockIdx.x >> 3, i0 = (blockIdx.x & 7) * 64;
  int tid = threadIdx.x, w = tid >> 6, l = tid & 63;
  __shared__ u16 tile[64][130];  // +2 pad: conflict-free column reads
  int d0 = 2 * l;
  float2 hd2 = *(const float2*)(hds + b * 128 + d0);
  float2 av0 = *(const float2*)(a0 + d0);
  float2 av1 = *(const float2*)(a1 + d0);
  float2 av2 = *(const float2*)(a2 + d0);
  float2 av3 = *(const float2*)(a3 + d0);
  for (int rr = 0; rr < 16; ++rr) {
    int il = rr * 4 + w;
    size_t row = (size_t)b * 512 + i0 + il;
    float2 hv = *(const float2*)(h + row * 128 + d0);
    _Float16 f0 = (_Float16)hv.x, f1 = (_Float16)hv.y;
    u16 u0 = __builtin_bit_cast(u16, f0), u1 = __builtin_bit_cast(u16, f1);
    tile[il][d0] = u0;
    tile[il][d0 + 1] = u1;
    *(u32*)(h16 + row * 128 + d0) = (u32)u0 | ((u32)u1 << 16);
    float t0 = hv.x * hd2.x, t1 = hv.y * hd2.y;
    float p0 = t0 * av0.x + t1 * av0.y;
    float p1 = t0 * av1.x + t1 * av1.y;
    float p2 = t0 * av2.x + t1 * av2.y;
    float p3 = t0 * av3.x + t1 * av3.y;
    for (int off = 32; off >= 1; off >>= 1) {
      p0 += __shfl_xor(p0, off);
      p1 += __shfl_xor(p1, off);
      p2 += __shfl_xor(p2, off);
      p3 += __shfl_xor(p3, off);
    }
    if (l == 0) *(float4*)(s + row * 4) = make_float4(p0, p1, p2, p3);
  }
  __syncthreads();
  // transpose: thread t -> row d of h16T, half of the 64 i's
  int d = tid >> 1, hf = tid & 1;
  u32 wds[16];
#pragma unroll
  for (int k = 0; k < 16; ++k) {
    u32 lo = tile[32 * hf + 2 * k][d];
    u32 hi = tile[32 * hf + 2 * k + 1][d];
    wds[k] = lo | (hi << 16);
  }
  uint4* dst = (uint4*)(h16T + ((size_t)b * 128 + d) * 512 + i0 + 32 * hf);
  dst[0] = make_uint4(wds[0], wds[1], wds[2], wds[3]);
  dst[1] = make_uint4(wds[4], wds[5], wds[6], wds[7]);
  dst[2] = make_uint4(wds[8], wds[9], wds[10], wds[11]);
  dst[3] = make_uint4(wds[12], wds[13], wds[14], wds[15]);
}

// ---------------- Kernel C: fused 4-head QK + select + online softmax + PV ----------------
// block = 256 thr (4 waves), wave w owns head w. i-tile = 32 rows, j-step = 64.
__global__ __launch_bounds__(256) void k_attn(const float* __restrict__ h,
                                              const u16* __restrict__ h16,
                                              const u16* __restrict__ h16T,
                                              const float* __restrict__ s,
                                              const int* __restrict__ adj,
                                              const float* __restrict__ a0,
                                              const float* __restrict__ a1,
                                              const float* __restrict__ a2,
                                              const float* __restrict__ a3,
                                              float* __restrict__ out) {
  int bid = blockIdx.x;
  int wg = (bid & 7) * 128 + (bid >> 3);  // XCD swizzle (1024 % 8 == 0, bijective)
  int b = wg >> 4, i0 = (wg & 15) * 32;
  int tid = threadIdx.x, w = tid >> 6, l = tid & 63;
  int l15 = l & 15, l4 = l >> 4;

  __shared__ u16 Kj[64 * 128];    // row-major [j][d], 16B-chunk XOR swizzled
  __shared__ u16 KjT[128 * 64];   // [d][j], swizzled
  __shared__ float sel[32 * 64];  // selected logits
  __shared__ u16 Pt[32 * 64];     // P tile f16, swizzled
  __shared__ float mrow[32], lrow[32], srow[32];

  const float* aw = (w == 0) ? a0 : (w == 1) ? a1 : (w == 2) ? a2 : a3;

  // Q fragments for head w: rows i0..i0+31 of h scaled by a_w, f16.
  // A-frag layout: row = l&15, k = 8*(l>>4)+e within each 32-k step.
  half8 qf[2][4];
#pragma unroll
  for (int R = 0; R < 2; ++R) {
    int r = 16 * R + l15;
    const float* hp = h + ((size_t)b * 512 + i0 + r) * 128;
#pragma unroll
    for (int ks = 0; ks < 4; ++ks) {
      int db = ks * 32 + l4 * 8;
      float4 h0 = *(const float4*)(hp + db);
      float4 h1 = *(const float4*)(hp + db + 4);
      float4 A0 = *(const float4*)(aw + db);
      float4 A1 = *(const float4*)(aw + db + 4);
      half8 q;
      q[0] = (_Float16)(h0.x * A0.x); q[1] = (_Float16)(h0.y * A0.y);
      q[2] = (_Float16)(h0.z * A0.z); q[3] = (_Float16)(h0.w * A0.w);
      q[4] = (_Float16)(h1.x * A1.x); q[5] = (_Float16)(h1.y * A1.y);
      q[6] = (_Float16)(h1.z * A1.z); q[7] = (_Float16)(h1.w * A1.w);
      qf[R][ks] = q;
    }
  }
  // s_i for head w; C-frag row = 16R + 4*(l>>4) + e
  float si[2][4];
#pragma unroll
  for (int R = 0; R < 2; ++R)
#pragma unroll
    for (int e = 0; e < 4; ++e)
      si[R][e] = s[((size_t)b * 512 + i0 + 16 * R + 4 * l4 + e) * 4 + w];

  if (tid < 32) { mrow[tid] = -__builtin_inff(); lrow[tid] = 0.f; }

  floatx4 pv[2][2];
#pragma unroll
  for (int R = 0; R < 2; ++R)
#pragma unroll
    for (int C = 0; C < 2; ++C) pv[R][C] = (floatx4){0.f, 0.f, 0.f, 0.f};

  const size_t hb16 = (size_t)b * 512 * 128;
  const size_t hTb = (size_t)b * 128 * 512;
  const size_t adjb = ((size_t)b * 512 + i0) * 512;
  const size_t sb = (size_t)b * 512 * 4;

  for (int jt = 0; jt < 8; ++jt) {
    int j0 = jt * 64;
    // ---- phase 1: stage Kj + KjT (swizzled), init sel ----
#pragma unroll
    for (int p = 0; p < 4; ++p) {
      int cid = p * 256 + tid;
      int j = cid >> 4, cl = cid & 15;
      uint4 v = *(const uint4*)(h16 + hb16 + (size_t)(j0 + j) * 128 + cl * 8);
      *(uint4*)((char*)Kj + (size_t)(j * 16 + (cl ^ (j & 15))) * 16) = v;
    }
#pragma unroll
    for (int p = 0; p < 4; ++p) {
      int cid = p * 256 + tid;
      int d = cid >> 3, cl = cid & 7;
      uint4 v = *(const uint4*)(h16T + hTb + (size_t)d * 512 + j0 + cl * 8);
      *(uint4*)((char*)KjT + (size_t)(d * 8 + (cl ^ (d & 7))) * 16) = v;
    }
    {
      float4 mv = make_float4(MASKV, MASKV, MASKV, MASKV);
      *(float4*)(sel + tid * 8) = mv;
      *(float4*)(sel + tid * 8 + 4) = mv;
    }
    __syncthreads();

    // ---- phase 2: QK^T (head w) + select by adj ----
    floatx4 qk[2][4];
#pragma unroll
    for (int R = 0; R < 2; ++R)
#pragma unroll
      for (int C = 0; C < 4; ++C) qk[R][C] = (floatx4){0.f, 0.f, 0.f, 0.f};
#pragma unroll
    for (int ks = 0; ks < 4; ++ks) {
      half8 bf[4];
#pragma unroll
      for (int C = 0; C < 4; ++C) {
        int j = 16 * C + l15;
        int ch = ks * 4 + l4;
        bf[C] = *(const half8*)((char*)Kj + (size_t)(j * 16 + (ch ^ (j & 15))) * 16);
      }
#pragma unroll
      for (int R = 0; R < 2; ++R)
#pragma unroll
        for (int C = 0; C < 4; ++C)
          qk[R][C] = __builtin_amdgcn_mfma_f32_16x16x32_f16(qf[R][ks], bf[C], qk[R][C], 0, 0, 0);
    }
#pragma unroll
    for (int C = 0; C < 4; ++C) {
      int c = 16 * C + l15;
      float sj = s[sb + (size_t)(j0 + c) * 4 + w];
#pragma unroll
      for (int R = 0; R < 2; ++R) {
#pragma unroll
        for (int e = 0; e < 4; ++e) {
          int r = 16 * R + 4 * l4 + e;
          int av = adj[adjb + (size_t)r * 512 + j0 + c];
          if (av == w + 1) {
            float x = qk[R][C][e] + si[R][e] + sj;
            x = (x > 0.f) ? x : LEAKY * x;
            sel[r * 64 + c] = x;
          }
        }
      }
    }
    __syncthreads();

    // ---- phase 3: online softmax over this 64-col tile ----
    {
      int r = tid >> 3, cg = tid & 7;
      float4 v0 = *(float4*)(sel + r * 64 + cg * 8);
      float4 v1 = *(float4*)(sel + r * 64 + cg * 8 + 4);
      float tmax = fmaxf(fmaxf(fmaxf(v0.x, v0.y), fmaxf(v0.z, v0.w)),
                         fmaxf(fmaxf(v1.x, v1.y), fmaxf(v1.z, v1.w)));
      tmax = fmaxf(tmax, __shfl_xor(tmax, 1));
      tmax = fmaxf(tmax, __shfl_xor(tmax, 2));
      tmax = fmaxf(tmax, __shfl_xor(tmax, 4));
      float mo = mrow[r];
      float mn = fmaxf(mo, tmax);
      float sc = __expf(mo - mn);
      float p0 = __expf(v0.x - mn), p1 = __expf(v0.y - mn);
      float p2 = __expf(v0.z - mn), p3 = __expf(v0.w - mn);
      float p4 = __expf(v1.x - mn), p5 = __expf(v1.y - mn);
      float p6 = __expf(v1.z - mn), p7 = __expf(v1.w - mn);
      half8 p8;
      p8[0] = (_Float16)p0; p8[1] = (_Float16)p1; p8[2] = (_Float16)p2; p8[3] = (_Float16)p3;
      p8[4] = (_Float16)p4; p8[5] = (_Float16)p5; p8[6] = (_Float16)p6; p8[7] = (_Float16)p7;
      *(half8*)((char*)Pt + (size_t)(r * 8 + (cg ^ (r & 7))) * 16) = p8;
      float ls = ((p0 + p1) + (p2 + p3)) + ((p4 + p5) + (p6 + p7));
      ls += __shfl_xor(ls, 1);
      ls += __shfl_xor(ls, 2);
      ls += __shfl_xor(ls, 4);
      if (cg == 0) { lrow[r] = lrow[r] * sc + ls; mrow[r] = mn; srow[r] = sc; }
    }
    __syncthreads();

    // ---- phase 4: rescale acc + PV (wave w owns d-cols 32w..32w+31) ----
#pragma unroll
    for (int R = 0; R < 2; ++R)
#pragma unroll
      for (int e = 0; e < 4; ++e) {
        float scv = srow[16 * R + 4 * l4 + e];
        pv[R][0][e] *= scv;
        pv[R][1][e] *= scv;
      }
#pragma unroll
    for (int ks = 0; ks < 2; ++ks) {
      half8 pa[2], vb[2];
#pragma unroll
      for (int R = 0; R < 2; ++R) {
        int pr = 16 * R + l15;
        int ch = ks * 4 + l4;
        pa[R] = *(const half8*)((char*)Pt + (size_t)(pr * 8 + (ch ^ (pr & 7))) * 16);
      }
#pragma unroll
      for (int C = 0; C < 2; ++C) {
        int d = 32 * w + 16 * C + l15;
        int ch = ks * 4 + l4;
        vb[C] = *(const half8*)((char*)KjT + (size_t)(d * 8 + (ch ^ (d & 7))) * 16);
      }
#pragma unroll
      for (int R = 0; R < 2; ++R)
#pragma unroll
        for (int C = 0; C < 2; ++C)
          pv[R][C] = __builtin_amdgcn_mfma_f32_16x16x32_f16(pa[R], vb[C], pv[R][C], 0, 0, 0);
    }
    __syncthreads();
  }

  // epilogue: divide by l, write out
#pragma unroll
  for (int R = 0; R < 2; ++R)
#pragma unroll
    for (int e = 0; e < 4; ++e) {
      int r = 16 * R + 4 * l4 + e;
      float inv = 1.0f / lrow[r];
#pragma unroll
      for (int C = 0; C < 2; ++C) {
        int d = 32 * w + 16 * C + l15;
        out[((size_t)b * 512 + i0 + r) * 128 + d] = pv[R][C][e] * inv;
      }
    }
}

extern "C" void kernel_launch(void* const* d_in, const int* in_sizes, int n_in,
                              void* d_out, int out_size, void* d_ws, size_t ws_size,
                              hipStream_t stream) {
  const float* hl = (const float*)d_in[0];
  const float* ht = (const float*)d_in[1];
  const float* ie = (const float*)d_in[2];
  const float* h  = (const float*)d_in[3];
  const int* adj  = (const int*)d_in[4];
  const float* wd = (const float*)d_in[5];
  const float* a0 = (const float*)d_in[6];
  const float* a1 = (const float*)d_in[7];
  const float* a2 = (const float*)d_in[8];
  const float* a3 = (const float*)d_in[9];
  // bias (d_in[10]) is unused by the reference.

  // ws layout (requires ~17.3 MB):
  float* hds = (float*)d_ws;                              // 64*128*4      = 32 KB
  float* s   = (float*)((char*)d_ws + 32768);             // 64*512*4*4    = 512 KB
  u16* h16   = (u16*)((char*)d_ws + 557056);              // 64*512*128*2  = 8 MB
  u16* h16T  = (u16*)((char*)d_ws + 8945664);             // 64*128*512*2  = 8 MB
  float* o   = (float*)d_out;

  k_hds<<<64, 128, 0, stream>>>(hl, ht, ie, wd, hds);
  k_prep<<<512, 256, 0, stream>>>(h, hds, a0, a1, a2, a3, s, h16, h16T);
  k_attn<<<1024, 256, 0, stream>>>(h, h16, h16T, s, adj, a0, a1, a2, a3, o);
}